// Round 3
// baseline (188.062 us; speedup 1.0000x reference)
//
#include <hip/hip_runtime.h>
#include <hip/hip_bf16.h>
#include <stdint.h>

#define DIM   1024
#define NH    16
#define HDIM  64
#define SEQ   2048
#define BATCH 2
#define BHN   32            // BATCH*NH
#define MTOK  4096          // BATCH*SEQ
#define SC2   0.18033688f   // (1/sqrt(64)) * log2(e)

using u16 = unsigned short;
using u32 = unsigned int;
typedef __attribute__((ext_vector_type(8))) short short8;   // MFMA A/B frag (8 bf16)
typedef __attribute__((ext_vector_type(4))) float f32x4;    // 16x16 MFMA C/D frag
typedef __attribute__((ext_vector_type(16))) float f32x16;  // 32x32 MFMA C/D frag

__device__ __forceinline__ u16 f2bf(float f) {
  __hip_bfloat16 h = __float2bfloat16(f);
  return *reinterpret_cast<u16*>(&h);
}
__device__ __forceinline__ float bf2f(u16 u) {
  u32 v = ((u32)u) << 16;
  return __builtin_bit_cast(float, v);
}
__device__ __forceinline__ u32 pk2(float lo, float hi) {
  return (u32)f2bf(lo) | ((u32)f2bf(hi) << 16);
}

// async global->LDS, 16B per lane. lds base must be wave-uniform; gsrc per-lane.
__device__ __forceinline__ void gload16(const void* g, void* lds) {
  __builtin_amdgcn_global_load_lds(
      (const __attribute__((address_space(1))) u32*)g,
      (__attribute__((address_space(3))) u32*)lds, 16, 0, 0);
}

// ---------------- fp32 -> bf16 convert ----------------
__global__ void k_f2b(const float4* __restrict__ src, ushort4* __restrict__ dst, int n4) {
  int i = blockIdx.x * blockDim.x + threadIdx.x;
  if (i < n4) {
    float4 v = src[i];
    ushort4 o;
    o.x = f2bf(v.x); o.y = f2bf(v.y); o.z = f2bf(v.z); o.w = f2bf(v.w);
    dst[i] = o;
  }
}

// ---------------- RoPE cos/sin table ----------------
__global__ void k_tab(float2* __restrict__ tab) {
  int i = blockIdx.x * blockDim.x + threadIdx.x;   // SEQ*32 threads
  int n = i >> 5, f = i & 31;
  float inv = powf(10000.f, -(2.f * f) / 64.f);
  float ang = (float)n * inv;
  float s, c;
  sincosf(ang, &s, &c);
  tab[i] = make_float2(c, s);
}

// ---------------- in-place RoPE on q,k (layout (BH, SEQ, HDIM) bf16) ----------------
__global__ void k_rope(u16* __restrict__ qb, u16* __restrict__ kb, const float2* __restrict__ tab) {
  int i = blockIdx.x * blockDim.x + threadIdx.x;   // 2 * BHN * SEQ * 8
  int c   = i & 7;
  int n   = (i >> 3) & (SEQ - 1);
  int bh  = (i >> 14) & 31;
  int arr = i >> 19;
  u16* base = (arr ? kb : qb) + (((size_t)bh * SEQ + n) * HDIM + c * 8);
  uint4 v = *reinterpret_cast<uint4*>(base);
  u32 w[4] = {v.x, v.y, v.z, v.w};
  const float2* t = tab + n * 32 + c * 4;
#pragma unroll
  for (int j = 0; j < 4; j++) {
    float e = bf2f((u16)(w[j] & 0xffff));
    float o = bf2f((u16)(w[j] >> 16));
    float2 cs = t[j];
    float en = e * cs.x - o * cs.y;
    float on = e * cs.y + o * cs.x;
    w[j] = (u32)f2bf(en) | ((u32)f2bf(on) << 16);
  }
  *reinterpret_cast<uint4*>(base) = make_uint4(w[0], w[1], w[2], w[3]);
}

// ---------------- bf16 GEMM (unchanged) ----------------
template <int EPI>
__global__ __launch_bounds__(256, 2) void k_gemm(
    const u16* __restrict__ A, const u16* __restrict__ Bt,
    const float* __restrict__ bias, int K,
    float* __restrict__ out_f, u16* __restrict__ qb, u16* __restrict__ kb, u16* __restrict__ vtb) {
  __shared__ u16 As[128 * 64];
  __shared__ u16 Bs[128 * 64];
  const int tid = threadIdx.x;
  const int wid = tid >> 6, lane = tid & 63;
  const int lq = lane & 15, g = lane >> 4;
  const int wr = wid >> 1, wc = wid & 1;
  const int brow = blockIdx.y * 128;
  const int bcol = blockIdx.x * 128;
  f32x4 acc[4][4] = {};
  const u16* Ab = A + (size_t)brow * K;
  const u16* Bb = Bt + (size_t)bcol * K;

  for (int k0 = 0; k0 < K; k0 += 64) {
#pragma unroll
    for (int t = 0; t < 4; t++) {
      int rl = wid * 32 + t * 8 + (lane >> 3);
      int cs = (lane & 7) ^ (rl & 7);
      gload16(Ab + (size_t)rl * K + k0 + cs * 8, &As[(wid * 32 + t * 8) * 64]);
      gload16(Bb + (size_t)rl * K + k0 + cs * 8, &Bs[(wid * 32 + t * 8) * 64]);
    }
    __syncthreads();
#pragma unroll
    for (int kc = 0; kc < 2; kc++) {
      short8 af[4], bfr[4];
#pragma unroll
      for (int mt = 0; mt < 4; mt++) {
        int r = wr * 64 + mt * 16 + lq;
        af[mt] = *reinterpret_cast<const short8*>(&As[r * 64 + (((kc * 4 + g) ^ (r & 7)) * 8)]);
      }
#pragma unroll
      for (int nt = 0; nt < 4; nt++) {
        int r = wc * 64 + nt * 16 + lq;
        bfr[nt] = *reinterpret_cast<const short8*>(&Bs[r * 64 + (((kc * 4 + g) ^ (r & 7)) * 8)]);
      }
#pragma unroll
      for (int mt = 0; mt < 4; mt++)
#pragma unroll
        for (int nt = 0; nt < 4; nt++)
          acc[mt][nt] = __builtin_amdgcn_mfma_f32_16x16x32_bf16(af[mt], bfr[nt], acc[mt][nt], 0, 0, 0);
    }
    __syncthreads();
  }

#pragma unroll
  for (int mt = 0; mt < 4; mt++) {
    int row0 = brow + wr * 64 + mt * 16 + g * 4;
#pragma unroll
    for (int nt = 0; nt < 4; nt++) {
      int col = bcol + wc * 64 + nt * 16 + lq;
      float bv = bias[col];
#pragma unroll
      for (int r = 0; r < 4; r++) {
        float v = acc[mt][nt][r] + bv;
        int rr = row0 + r;
        if (EPI == 0) {
          out_f[(size_t)rr * DIM + col] = v;
        } else {
          int which = col >> 10, hd = col & 1023, h = hd >> 6, d = hd & 63;
          int bb = rr >> 11, n = rr & 2047;
          u16 x = f2bf(v);
          if (which == 0)      qb[(((size_t)bb * NH + h) * SEQ + n) * HDIM + d] = x;
          else if (which == 1) kb[(((size_t)bb * NH + h) * SEQ + n) * HDIM + d] = x;
          else                 vtb[(((size_t)bb * NH + h) * HDIM + d) * SEQ + n] = x;
        }
      }
    }
  }
}

// ---------------- flash attention, 8 waves, in-block KV-split x2 ----------------
// grid (SEQ/128, BHN), 512 threads. Wave w: q-rows (w&3)*32.., kv-half (w>>2).
// Each half: 16 kv-tiles of 64, double-buffered LDS. S^T = K*Q^T (32x32x16),
// per-lane online softmax (tree reduces), P in-register via pack+permlane32_swap,
// O^T = V^T*P^T. Halves merged in-block via LDS (aliased over K/V region).
__global__ __launch_bounds__(512, 4) void k_attn(
    const u16* __restrict__ qb, const u16* __restrict__ kb,
    const u16* __restrict__ vtb, u16* __restrict__ aout) {
  __shared__ __align__(16) char smem[65536];   // [K: 2half x 2buf x 8KB][V: same]
  float* Om = (float*)smem;                    // merge alias: [128][65] f32
  float* Ml = (float*)(smem + 128 * 65 * 4);   // merge alias: [128][2]

  const int tid = threadIdx.x;
  const int wid = tid >> 6, lane = tid & 63;
  const int wq = wid & 3, sh = wid >> 2;
  const int l31 = lane & 31, h = lane >> 5;
  const int bh = blockIdx.y, b = bh >> 4, hh = bh & 15;
  const int q0 = blockIdx.x * 128 + wq * 32;

  const u16* kbase = kb + (size_t)bh * SEQ * HDIM;
  const u16* vbase = vtb + (size_t)bh * HDIM * SEQ;

  // Q B-frags: chunk c -> d = c*16 + h*8 + j
  const u16* qrow = qb + ((size_t)bh * SEQ + q0 + l31) * HDIM;
  short8 qf[4];
#pragma unroll
  for (int c = 0; c < 4; c++)
    qf[c] = *reinterpret_cast<const short8*>(qrow + c * 16 + h * 8);

  // hoisted swizzled LDS byte-offsets (row l31; +4096 for rows 32-63)
  int koff[4];
#pragma unroll
  for (int c = 0; c < 4; c++)
    koff[c] = l31 * 128 + (((2 * c + h) ^ (l31 & 7)) << 4);

  f32x16 oA = {}, oB = {};
  float m = -INFINITY, lsum = 0.f;

  char* kreg = smem + sh * 16384;           // this half's K double-buffer
  char* vreg = smem + 32768 + sh * 16384;   // this half's V double-buffer

  auto stage = [&](int buf, int kv0) {      // kv0 absolute
#pragma unroll
    for (int t = 0; t < 2; t++) {
      int rl = wq * 16 + t * 8 + (lane >> 3);
      int cs = (lane & 7) ^ (rl & 7);       // pre-swizzled global source
      gload16(kbase + (size_t)(kv0 + rl) * HDIM + cs * 8, kreg + buf * 8192 + (wq * 16 + t * 8) * 128);
      gload16(vbase + (size_t)rl * SEQ + kv0 + cs * 8, vreg + buf * 8192 + (wq * 16 + t * 8) * 128);
    }
  };

  const int kvbase = sh * (SEQ / 2);
  stage(0, kvbase);
  __syncthreads();

  for (int t = 0; t < SEQ / 128; ++t) {     // 16 tiles per half
    const int cur = t & 1;
    if (t + 1 < SEQ / 128) stage(cur ^ 1, kvbase + (t + 1) * 64);
    const char* kbp = kreg + cur * 8192;
    const char* vbp = vreg + cur * 8192;

    // S^T = K * Q^T : s0 = kv 0..31 of tile, s1 = kv 32..63; lane col q = l31
    f32x16 s0 = {}, s1 = {};
#pragma unroll
    for (int c = 0; c < 4; c++) {
      short8 k0 = *reinterpret_cast<const short8*>(kbp + koff[c]);
      short8 k1 = *reinterpret_cast<const short8*>(kbp + koff[c] + 4096);
      s0 = __builtin_amdgcn_mfma_f32_32x32x16_bf16(k0, qf[c], s0, 0, 0, 0);
      s1 = __builtin_amdgcn_mfma_f32_32x32x16_bf16(k1, qf[c], s1, 0, 0, 0);
    }

    // V A-frags issued early: latency hides under softmax VALU
    short8 vf0[4], vf1[4];
#pragma unroll
    for (int c = 0; c < 4; c++) {
      vf0[c] = *reinterpret_cast<const short8*>(vbp + koff[c]);
      vf1[c] = *reinterpret_cast<const short8*>(vbp + koff[c] + 4096);
    }

    // online softmax; lane owns q = l31 (paired across lane^32). Tree reduces.
    float tm[16];
#pragma unroll
    for (int r = 0; r < 16; r++) tm[r] = fmaxf(s0[r], s1[r]);
#pragma unroll
    for (int st = 8; st >= 1; st >>= 1)
#pragma unroll
      for (int r = 0; r < 8; r++)
        if (r < st) tm[r] = fmaxf(tm[r], tm[r + st]);
    float tmax = fmaxf(tm[0], __shfl_xor(tm[0], 32));

    float alpha = 1.f;
    if (__any(tmax - m > 61.0f)) {     // defer-max: p bounded by 2^11
      float mnew = fmaxf(m, tmax);
      alpha = exp2f((m - mnew) * SC2);
      m = mnew;
#pragma unroll
      for (int r = 0; r < 16; r++) { oA[r] *= alpha; oB[r] *= alpha; }
    }
#pragma unroll
    for (int r = 0; r < 16; r++) s0[r] = exp2f((s0[r] - m) * SC2);
#pragma unroll
    for (int r = 0; r < 16; r++) s1[r] = exp2f((s1[r] - m) * SC2);
    float ps[16];
#pragma unroll
    for (int r = 0; r < 16; r++) ps[r] = s0[r] + s1[r];
#pragma unroll
    for (int st = 8; st >= 1; st >>= 1)
#pragma unroll
      for (int r = 0; r < 8; r++)
        if (r < st) ps[r] += ps[r + st];
    float psum = ps[0] + __shfl_xor(ps[0], 32);
    lsum = lsum * alpha + psum;

    // pack P to bf16 B-frags: 4 packs + 2 permlane32_swap per chunk (T12)
    short8 pf[4];
    {
      union { u32 u[4]; short8 v; } pp;
      u32 a0, a1, b0, b1;
      a0 = pk2(s0[0], s0[1]);  a1 = pk2(s0[2], s0[3]);
      b0 = pk2(s0[4], s0[5]);  b1 = pk2(s0[6], s0[7]);
      { auto r0 = __builtin_amdgcn_permlane32_swap(a0, b0, false, false);
        auto r1 = __builtin_amdgcn_permlane32_swap(a1, b1, false, false);
        pp.u[0] = r0[0]; pp.u[1] = r1[0]; pp.u[2] = r0[1]; pp.u[3] = r1[1]; pf[0] = pp.v; }
      a0 = pk2(s0[8], s0[9]);   a1 = pk2(s0[10], s0[11]);
      b0 = pk2(s0[12], s0[13]); b1 = pk2(s0[14], s0[15]);
      { auto r0 = __builtin_amdgcn_permlane32_swap(a0, b0, false, false);
        auto r1 = __builtin_amdgcn_permlane32_swap(a1, b1, false, false);
        pp.u[0] = r0[0]; pp.u[1] = r1[0]; pp.u[2] = r0[1]; pp.u[3] = r1[1]; pf[1] = pp.v; }
      a0 = pk2(s1[0], s1[1]);  a1 = pk2(s1[2], s1[3]);
      b0 = pk2(s1[4], s1[5]);  b1 = pk2(s1[6], s1[7]);
      { auto r0 = __builtin_amdgcn_permlane32_swap(a0, b0, false, false);
        auto r1 = __builtin_amdgcn_permlane32_swap(a1, b1, false, false);
        pp.u[0] = r0[0]; pp.u[1] = r1[0]; pp.u[2] = r0[1]; pp.u[3] = r1[1]; pf[2] = pp.v; }
      a0 = pk2(s1[8], s1[9]);   a1 = pk2(s1[10], s1[11]);
      b0 = pk2(s1[12], s1[13]); b1 = pk2(s1[14], s1[15]);
      { auto r0 = __builtin_amdgcn_permlane32_swap(a0, b0, false, false);
        auto r1 = __builtin_amdgcn_permlane32_swap(a1, b1, false, false);
        pp.u[0] = r0[0]; pp.u[1] = r1[0]; pp.u[2] = r0[1]; pp.u[3] = r1[1]; pf[3] = pp.v; }
    }

    // O^T += V^T * P^T : oA = d 0..31, oB = d 32..63; lane col q = l31
#pragma unroll
    for (int c = 0; c < 4; c++) {
      oA = __builtin_amdgcn_mfma_f32_32x32x16_bf16(vf0[c], pf[c], oA, 0, 0, 0);
      oB = __builtin_amdgcn_mfma_f32_32x32x16_bf16(vf1[c], pf[c], oB, 0, 0, 0);
    }
    __syncthreads();
  }

  // ---- in-block merge of the two kv-halves (LDS aliases K/V region) ----
  const int ql = wq * 32 + l31;     // q-row within block
  if (sh == 1) {
    if (h == 0) { Ml[ql * 2] = m; Ml[ql * 2 + 1] = lsum; }
#pragma unroll
    for (int g = 0; g < 4; g++)
#pragma unroll
      for (int i = 0; i < 4; i++) {
        Om[ql * 65 + 8 * g + 4 * h + i]      = oA[4 * g + i];
        Om[ql * 65 + 32 + 8 * g + 4 * h + i] = oB[4 * g + i];
      }
  }
  __syncthreads();
  if (sh == 0) {
    float m1 = Ml[ql * 2], l1 = Ml[ql * 2 + 1];
    float M = fmaxf(m, m1);
    float a0 = exp2f((m - M) * SC2);
    float a1 = exp2f((m1 - M) * SC2);
    float invl = 1.0f / (lsum * a0 + l1 * a1);

    int n = q0 + l31;
    u16* op = aout + ((size_t)(b * SEQ + n)) * DIM + hh * HDIM;
#pragma unroll
    for (int g = 0; g < 4; g++) {
      float vA[4], vB[4];
#pragma unroll
      for (int i = 0; i < 4; i++) {
        vA[i] = (oA[4 * g + i] * a0 + Om[ql * 65 + 8 * g + 4 * h + i] * a1) * invl;
        vB[i] = (oB[4 * g + i] * a0 + Om[ql * 65 + 32 + 8 * g + 4 * h + i] * a1) * invl;
      }
      *reinterpret_cast<uint2*>(op + 8 * g + 4 * h) = make_uint2(pk2(vA[0], vA[1]), pk2(vA[2], vA[3]));
      *reinterpret_cast<uint2*>(op + 32 + 8 * g + 4 * h) = make_uint2(pk2(vB[0], vB[1]), pk2(vB[2], vB[3]));
    }
  }
}

// ---------------- launch ----------------
extern "C" void kernel_launch(void* const* d_in, const int* in_sizes, int n_in,
                              void* d_out, int out_size, void* d_ws, size_t ws_size,
                              hipStream_t stream) {
  (void)in_sizes; (void)n_in; (void)out_size; (void)ws_size;
  const float* x      = (const float*)d_in[0];
  const float* qkv_w  = (const float*)d_in[1];
  const float* qkv_b  = (const float*)d_in[2];
  const float* proj_w = (const float*)d_in[3];
  const float* proj_b = (const float*)d_in[4];
  float* out = (float*)d_out;

  char* w = (char*)d_ws;
  u16* xb     = (u16*)w;  w += (size_t)MTOK * DIM * 2;
  u16* wqkvb  = (u16*)w;  w += (size_t)3 * DIM * DIM * 2;
  u16* wprojb = (u16*)w;  w += (size_t)DIM * DIM * 2;
  u16* qb     = (u16*)w;  w += (size_t)BHN * SEQ * HDIM * 2;
  u16* kb     = (u16*)w;  w += (size_t)BHN * SEQ * HDIM * 2;
  u16* vtb    = (u16*)w;  w += (size_t)BHN * SEQ * HDIM * 2;
  u16* aout   = (u16*)w;  w += (size_t)MTOK * DIM * 2;
  float2* tab = (float2*)w;

  k_f2b<<<MTOK * DIM / 4 / 256, 256, 0, stream>>>((const float4*)x, (ushort4*)xb, MTOK * DIM / 4);
  k_f2b<<<3 * DIM * DIM / 4 / 256, 256, 0, stream>>>((const float4*)qkv_w, (ushort4*)wqkvb, 3 * DIM * DIM / 4);
  k_f2b<<<DIM * DIM / 4 / 256, 256, 0, stream>>>((const float4*)proj_w, (ushort4*)wprojb, DIM * DIM / 4);
  k_tab<<<SEQ * 32 / 256, 256, 0, stream>>>(tab);

  k_gemm<1><<<dim3(3 * DIM / 128, MTOK / 128), 256, 0, stream>>>(
      xb, wqkvb, qkv_b, DIM, nullptr, qb, kb, vtb);

  k_rope<<<2 * BHN * SEQ * 8 / 256, 256, 0, stream>>>(qb, kb, tab);

  k_attn<<<dim3(SEQ / 128, BHN), 512, 0, stream>>>(qb, kb, vtb, aout);

  k_gemm<0><<<dim3(DIM / 128, MTOK / 128), 256, 0, stream>>>(
      aout, wprojb, proj_b, DIM, out, nullptr, nullptr, nullptr);
}

// Round 4
// 149.832 us; speedup vs baseline: 1.2552x; 1.2552x over previous
//
#include <hip/hip_runtime.h>
#include <hip/hip_bf16.h>
#include <stdint.h>

#define DIM   1024
#define NH    16
#define HDIM  64
#define SEQ   2048
#define BATCH 2
#define BHN   32            // BATCH*NH
#define MTOK  4096          // BATCH*SEQ
#define SC2   0.18033688f   // (1/sqrt(64)) * log2(e)

using u16 = unsigned short;
using u32 = unsigned int;
typedef __attribute__((ext_vector_type(8))) short short8;   // MFMA A/B frag (8 bf16)
typedef __attribute__((ext_vector_type(4))) float f32x4;    // 16x16 MFMA C/D frag
typedef __attribute__((ext_vector_type(16))) float f32x16;  // 32x32 MFMA C/D frag

__device__ __forceinline__ u16 f2bf(float f) {
  __hip_bfloat16 h = __float2bfloat16(f);
  return *reinterpret_cast<u16*>(&h);
}
__device__ __forceinline__ float bf2f(u16 u) {
  u32 v = ((u32)u) << 16;
  return __builtin_bit_cast(float, v);
}
__device__ __forceinline__ u32 pk2(float lo, float hi) {
  return (u32)f2bf(lo) | ((u32)f2bf(hi) << 16);
}
// hardware packed f32->bf16 (RNE), 1 instr for 2 values
__device__ __forceinline__ u32 cvtpk(float lo, float hi) {
  u32 r;
  asm("v_cvt_pk_bf16_f32 %0, %1, %2" : "=v"(r) : "v"(lo), "v"(hi));
  return r;
}

// async global->LDS, 16B per lane. lds base must be wave-uniform; gsrc per-lane.
__device__ __forceinline__ void gload16(const void* g, void* lds) {
  __builtin_amdgcn_global_load_lds(
      (const __attribute__((address_space(1))) u32*)g,
      (__attribute__((address_space(3))) u32*)lds, 16, 0, 0);
}

// ---------------- fp32 -> bf16 convert ----------------
__global__ void k_f2b(const float4* __restrict__ src, ushort4* __restrict__ dst, int n4) {
  int i = blockIdx.x * blockDim.x + threadIdx.x;
  if (i < n4) {
    float4 v = src[i];
    ushort4 o;
    o.x = f2bf(v.x); o.y = f2bf(v.y); o.z = f2bf(v.z); o.w = f2bf(v.w);
    dst[i] = o;
  }
}

// ---------------- RoPE cos/sin table ----------------
__global__ void k_tab(float2* __restrict__ tab) {
  int i = blockIdx.x * blockDim.x + threadIdx.x;   // SEQ*32 threads
  int n = i >> 5, f = i & 31;
  float inv = powf(10000.f, -(2.f * f) / 64.f);
  float ang = (float)n * inv;
  float s, c;
  sincosf(ang, &s, &c);
  tab[i] = make_float2(c, s);
}

// ---------------- in-place RoPE on q,k (layout (BH, SEQ, HDIM) bf16) ----------------
__global__ void k_rope(u16* __restrict__ qb, u16* __restrict__ kb, const float2* __restrict__ tab) {
  int i = blockIdx.x * blockDim.x + threadIdx.x;   // 2 * BHN * SEQ * 8
  int c   = i & 7;
  int n   = (i >> 3) & (SEQ - 1);
  int bh  = (i >> 14) & 31;
  int arr = i >> 19;
  u16* base = (arr ? kb : qb) + (((size_t)bh * SEQ + n) * HDIM + c * 8);
  uint4 v = *reinterpret_cast<uint4*>(base);
  u32 w[4] = {v.x, v.y, v.z, v.w};
  const float2* t = tab + n * 32 + c * 4;
#pragma unroll
  for (int j = 0; j < 4; j++) {
    float e = bf2f((u16)(w[j] & 0xffff));
    float o = bf2f((u16)(w[j] >> 16));
    float2 cs = t[j];
    float en = e * cs.x - o * cs.y;
    float on = e * cs.y + o * cs.x;
    w[j] = (u32)f2bf(en) | ((u32)f2bf(on) << 16);
  }
  *reinterpret_cast<uint4*>(base) = make_uint4(w[0], w[1], w[2], w[3]);
}

// ---------------- bf16 GEMM (unchanged) ----------------
template <int EPI>
__global__ __launch_bounds__(256, 2) void k_gemm(
    const u16* __restrict__ A, const u16* __restrict__ Bt,
    const float* __restrict__ bias, int K,
    float* __restrict__ out_f, u16* __restrict__ qb, u16* __restrict__ kb, u16* __restrict__ vtb) {
  __shared__ u16 As[128 * 64];
  __shared__ u16 Bs[128 * 64];
  const int tid = threadIdx.x;
  const int wid = tid >> 6, lane = tid & 63;
  const int lq = lane & 15, g = lane >> 4;
  const int wr = wid >> 1, wc = wid & 1;
  const int brow = blockIdx.y * 128;
  const int bcol = blockIdx.x * 128;
  f32x4 acc[4][4] = {};
  const u16* Ab = A + (size_t)brow * K;
  const u16* Bb = Bt + (size_t)bcol * K;

  for (int k0 = 0; k0 < K; k0 += 64) {
#pragma unroll
    for (int t = 0; t < 4; t++) {
      int rl = wid * 32 + t * 8 + (lane >> 3);
      int cs = (lane & 7) ^ (rl & 7);
      gload16(Ab + (size_t)rl * K + k0 + cs * 8, &As[(wid * 32 + t * 8) * 64]);
      gload16(Bb + (size_t)rl * K + k0 + cs * 8, &Bs[(wid * 32 + t * 8) * 64]);
    }
    __syncthreads();
#pragma unroll
    for (int kc = 0; kc < 2; kc++) {
      short8 af[4], bfr[4];
#pragma unroll
      for (int mt = 0; mt < 4; mt++) {
        int r = wr * 64 + mt * 16 + lq;
        af[mt] = *reinterpret_cast<const short8*>(&As[r * 64 + (((kc * 4 + g) ^ (r & 7)) * 8)]);
      }
#pragma unroll
      for (int nt = 0; nt < 4; nt++) {
        int r = wc * 64 + nt * 16 + lq;
        bfr[nt] = *reinterpret_cast<const short8*>(&Bs[r * 64 + (((kc * 4 + g) ^ (r & 7)) * 8)]);
      }
#pragma unroll
      for (int mt = 0; mt < 4; mt++)
#pragma unroll
        for (int nt = 0; nt < 4; nt++)
          acc[mt][nt] = __builtin_amdgcn_mfma_f32_16x16x32_bf16(af[mt], bfr[nt], acc[mt][nt], 0, 0, 0);
    }
    __syncthreads();
  }

#pragma unroll
  for (int mt = 0; mt < 4; mt++) {
    int row0 = brow + wr * 64 + mt * 16 + g * 4;
#pragma unroll
    for (int nt = 0; nt < 4; nt++) {
      int col = bcol + wc * 64 + nt * 16 + lq;
      float bv = bias[col];
#pragma unroll
      for (int r = 0; r < 4; r++) {
        float v = acc[mt][nt][r] + bv;
        int rr = row0 + r;
        if (EPI == 0) {
          out_f[(size_t)rr * DIM + col] = v;
        } else {
          int which = col >> 10, hd = col & 1023, h = hd >> 6, d = hd & 63;
          int bb = rr >> 11, n = rr & 2047;
          u16 x = f2bf(v);
          if (which == 0)      qb[(((size_t)bb * NH + h) * SEQ + n) * HDIM + d] = x;
          else if (which == 1) kb[(((size_t)bb * NH + h) * SEQ + n) * HDIM + d] = x;
          else                 vtb[(((size_t)bb * NH + h) * HDIM + d) * SEQ + n] = x;
        }
      }
    }
  }
}

// ---------------- flash attention, round-2 structure + T4/T5/T12/XCD fixes ----------------
// 1-D grid 512 blocks, 256 thr (4 waves x 32 q-rows, full KV sweep per wave).
// XCD swizzle: 4 heads per XCD -> per-XCD KV working set 2MB fits its L2.
// Pipeline: dbuf K/V, counted s_waitcnt vmcnt(4) + raw barriers (no vmcnt(0) drain).
// Softmax: per-lane, fmaf-folded exp2, max3 tree, cvt_pk packing, permlane32_swap.
__global__ __launch_bounds__(256, 2) void k_attn(
    const u16* __restrict__ qb, const u16* __restrict__ kb,
    const u16* __restrict__ vtb, u16* __restrict__ aout) {
  __shared__ __align__(16) char smem[32768];   // 2 buf x [K 8KB | V 8KB]
  const int tid = threadIdx.x;
  const int wid = tid >> 6, lane = tid & 63;
  const int l31 = lane & 31, h = lane >> 5;

  // XCD-aware decode: bid&7 = XCD; 4 consecutive heads per XCD
  const int bid = blockIdx.x;
  const int xcd = bid & 7, slot = bid >> 3;
  const int bh = xcd * 4 + (slot >> 4);
  const int qt = slot & 15;
  const int b = bh >> 4, hh = bh & 15;
  const int q0 = qt * 128 + wid * 32;

  const u16* kbase = kb + (size_t)bh * SEQ * HDIM;
  const u16* vbase = vtb + (size_t)bh * HDIM * SEQ;

  // Q B-frags: chunk c -> d = c*16 + h*8 + j
  const u16* qrow = qb + ((size_t)bh * SEQ + q0 + l31) * HDIM;
  short8 qf[4];
#pragma unroll
  for (int c = 0; c < 4; c++)
    qf[c] = *reinterpret_cast<const short8*>(qrow + c * 16 + h * 8);

  // hoisted swizzled LDS byte-offsets (row l31; +4096 for rows 32-63)
  int koff[4];
#pragma unroll
  for (int c = 0; c < 4; c++)
    koff[c] = l31 * 128 + (((2 * c + h) ^ (l31 & 7)) << 4);

  f32x16 oA = {}, oB = {};
  float m = -INFINITY, lsum = 0.f;

  auto stage = [&](int buf, int kv0) {   // 4 gloads/lane (2 K + 2 V)
    char* kd = smem + buf * 16384;
#pragma unroll
    for (int t = 0; t < 2; t++) {
      int rl = wid * 16 + t * 8 + (lane >> 3);
      int cs = (lane & 7) ^ (rl & 7);          // pre-swizzled global source
      gload16(kbase + (size_t)(kv0 + rl) * HDIM + cs * 8, kd + (wid * 16 + t * 8) * 128);
      gload16(vbase + (size_t)rl * SEQ + kv0 + cs * 8, kd + 8192 + (wid * 16 + t * 8) * 128);
    }
  };

  stage(0, 0);
  stage(1, 64);

  const int NT = SEQ / 64;
  for (int t = 0; t < NT; ++t) {
    const int cur = t & 1;
    // wait tile t's loads (4 newer from tile t+1 may stay in flight); all-waves barrier
    if (t < NT - 1) asm volatile("s_waitcnt vmcnt(4)" ::: "memory");
    else            asm volatile("s_waitcnt vmcnt(0)" ::: "memory");
    __builtin_amdgcn_s_barrier();

    const char* kbp = smem + cur * 16384;
    const char* vbp = kbp + 8192;

    // S^T = K * Q^T : s0 = kv 0..31 of tile, s1 = kv 32..63; lane col q = l31
    f32x16 s0 = {}, s1 = {};
    __builtin_amdgcn_s_setprio(1);
#pragma unroll
    for (int c = 0; c < 4; c++) {
      short8 k0 = *reinterpret_cast<const short8*>(kbp + koff[c]);
      short8 k1 = *reinterpret_cast<const short8*>(kbp + koff[c] + 4096);
      s0 = __builtin_amdgcn_mfma_f32_32x32x16_bf16(k0, qf[c], s0, 0, 0, 0);
      s1 = __builtin_amdgcn_mfma_f32_32x32x16_bf16(k1, qf[c], s1, 0, 0, 0);
    }
    __builtin_amdgcn_s_setprio(0);

    // V A-frags issued early: LDS latency hides under softmax VALU
    short8 vf0[4], vf1[4];
#pragma unroll
    for (int c = 0; c < 4; c++) {
      vf0[c] = *reinterpret_cast<const short8*>(vbp + koff[c]);
      vf1[c] = *reinterpret_cast<const short8*>(vbp + koff[c] + 4096);
    }

    // online softmax; lane owns q = l31 (paired across lane^32)
    float tm[8];
#pragma unroll
    for (int r = 0; r < 8; r++)
      tm[r] = fmaxf(fmaxf(s0[r], s1[r]), fmaxf(s0[r + 8], s1[r + 8]));
    float ta = fmaxf(fmaxf(tm[0], tm[1]), tm[2]);
    float tb = fmaxf(fmaxf(tm[3], tm[4]), tm[5]);
    float tc = fmaxf(tm[6], tm[7]);
    float tmax = fmaxf(fmaxf(ta, tb), tc);
    tmax = fmaxf(tmax, __shfl_xor(tmax, 32));

    float alpha = 1.f;
    if (__any(tmax - m > 61.0f)) {     // defer-max: p bounded by 2^11
      float mnew = fmaxf(m, tmax);
      alpha = exp2f((m - mnew) * SC2);
      m = mnew;
#pragma unroll
      for (int r = 0; r < 16; r++) { oA[r] *= alpha; oB[r] *= alpha; }
    }
    const float nms = -m * SC2;
#pragma unroll
    for (int r = 0; r < 16; r++) s0[r] = exp2f(fmaf(s0[r], SC2, nms));
#pragma unroll
    for (int r = 0; r < 16; r++) s1[r] = exp2f(fmaf(s1[r], SC2, nms));
    float pa = 0.f, pb = 0.f, pc = 0.f, pd = 0.f;
#pragma unroll
    for (int r = 0; r < 4; r++) {
      pa += s0[r] + s0[r + 4];
      pb += s0[r + 8] + s0[r + 12];
      pc += s1[r] + s1[r + 4];
      pd += s1[r + 8] + s1[r + 12];
    }
    float psum = (pa + pb) + (pc + pd);
    psum += __shfl_xor(psum, 32);
    lsum = lsum * alpha + psum;

    // pack P to bf16 B-frags: 4 cvt_pk + 2 permlane32_swap per chunk (T12)
    short8 pf[4];
    {
      union { u32 u[4]; short8 v; } pp;
      u32 a0, a1, b0, b1;
      a0 = cvtpk(s0[0], s0[1]);  a1 = cvtpk(s0[2], s0[3]);
      b0 = cvtpk(s0[4], s0[5]);  b1 = cvtpk(s0[6], s0[7]);
      { auto r0 = __builtin_amdgcn_permlane32_swap(a0, b0, false, false);
        auto r1 = __builtin_amdgcn_permlane32_swap(a1, b1, false, false);
        pp.u[0] = r0[0]; pp.u[1] = r1[0]; pp.u[2] = r0[1]; pp.u[3] = r1[1]; pf[0] = pp.v; }
      a0 = cvtpk(s0[8], s0[9]);   a1 = cvtpk(s0[10], s0[11]);
      b0 = cvtpk(s0[12], s0[13]); b1 = cvtpk(s0[14], s0[15]);
      { auto r0 = __builtin_amdgcn_permlane32_swap(a0, b0, false, false);
        auto r1 = __builtin_amdgcn_permlane32_swap(a1, b1, false, false);
        pp.u[0] = r0[0]; pp.u[1] = r1[0]; pp.u[2] = r0[1]; pp.u[3] = r1[1]; pf[1] = pp.v; }
      a0 = cvtpk(s1[0], s1[1]);  a1 = cvtpk(s1[2], s1[3]);
      b0 = cvtpk(s1[4], s1[5]);  b1 = cvtpk(s1[6], s1[7]);
      { auto r0 = __builtin_amdgcn_permlane32_swap(a0, b0, false, false);
        auto r1 = __builtin_amdgcn_permlane32_swap(a1, b1, false, false);
        pp.u[0] = r0[0]; pp.u[1] = r1[0]; pp.u[2] = r0[1]; pp.u[3] = r1[1]; pf[2] = pp.v; }
      a0 = cvtpk(s1[8], s1[9]);   a1 = cvtpk(s1[10], s1[11]);
      b0 = cvtpk(s1[12], s1[13]); b1 = cvtpk(s1[14], s1[15]);
      { auto r0 = __builtin_amdgcn_permlane32_swap(a0, b0, false, false);
        auto r1 = __builtin_amdgcn_permlane32_swap(a1, b1, false, false);
        pp.u[0] = r0[0]; pp.u[1] = r1[0]; pp.u[2] = r0[1]; pp.u[3] = r1[1]; pf[3] = pp.v; }
    }

    // O^T += V^T * P^T : oA = d 0..31, oB = d 32..63; lane col q = l31
    __builtin_amdgcn_s_setprio(1);
#pragma unroll
    for (int c = 0; c < 4; c++) {
      oA = __builtin_amdgcn_mfma_f32_32x32x16_bf16(vf0[c], pf[c], oA, 0, 0, 0);
      oB = __builtin_amdgcn_mfma_f32_32x32x16_bf16(vf1[c], pf[c], oB, 0, 0, 0);
    }
    __builtin_amdgcn_s_setprio(0);

    // all my LDS reads complete -> safe for others to overwrite after barrier
    asm volatile("s_waitcnt lgkmcnt(0)" ::: "memory");
    __builtin_amdgcn_s_barrier();
    if (t + 2 < NT) stage(cur, (t + 2) * 64);   // refill the buffer just freed
  }

  // epilogue: d = {0,32} + 8g + 4h + i ; n = q0 + l31
  float invl = 1.0f / lsum;
  int n = q0 + l31;
  u16* op = aout + ((size_t)(b * SEQ + n)) * DIM + hh * HDIM;
#pragma unroll
  for (int g = 0; g < 4; g++) {
    u32 w0 = pk2(oA[4 * g] * invl, oA[4 * g + 1] * invl);
    u32 w1 = pk2(oA[4 * g + 2] * invl, oA[4 * g + 3] * invl);
    *reinterpret_cast<uint2*>(op + 8 * g + 4 * h) = make_uint2(w0, w1);
    u32 x0 = pk2(oB[4 * g] * invl, oB[4 * g + 1] * invl);
    u32 x1 = pk2(oB[4 * g + 2] * invl, oB[4 * g + 3] * invl);
    *reinterpret_cast<uint2*>(op + 32 + 8 * g + 4 * h) = make_uint2(x0, x1);
  }
}

// ---------------- launch ----------------
extern "C" void kernel_launch(void* const* d_in, const int* in_sizes, int n_in,
                              void* d_out, int out_size, void* d_ws, size_t ws_size,
                              hipStream_t stream) {
  (void)in_sizes; (void)n_in; (void)out_size; (void)ws_size;
  const float* x      = (const float*)d_in[0];
  const float* qkv_w  = (const float*)d_in[1];
  const float* qkv_b  = (const float*)d_in[2];
  const float* proj_w = (const float*)d_in[3];
  const float* proj_b = (const float*)d_in[4];
  float* out = (float*)d_out;

  char* w = (char*)d_ws;
  u16* xb     = (u16*)w;  w += (size_t)MTOK * DIM * 2;
  u16* wqkvb  = (u16*)w;  w += (size_t)3 * DIM * DIM * 2;
  u16* wprojb = (u16*)w;  w += (size_t)DIM * DIM * 2;
  u16* qb     = (u16*)w;  w += (size_t)BHN * SEQ * HDIM * 2;
  u16* kb     = (u16*)w;  w += (size_t)BHN * SEQ * HDIM * 2;
  u16* vtb    = (u16*)w;  w += (size_t)BHN * SEQ * HDIM * 2;
  u16* aout   = (u16*)w;  w += (size_t)MTOK * DIM * 2;
  float2* tab = (float2*)w;

  k_f2b<<<MTOK * DIM / 4 / 256, 256, 0, stream>>>((const float4*)x, (ushort4*)xb, MTOK * DIM / 4);
  k_f2b<<<3 * DIM * DIM / 4 / 256, 256, 0, stream>>>((const float4*)qkv_w, (ushort4*)wqkvb, 3 * DIM * DIM / 4);
  k_f2b<<<DIM * DIM / 4 / 256, 256, 0, stream>>>((const float4*)proj_w, (ushort4*)wprojb, DIM * DIM / 4);
  k_tab<<<SEQ * 32 / 256, 256, 0, stream>>>(tab);

  k_gemm<1><<<dim3(3 * DIM / 128, MTOK / 128), 256, 0, stream>>>(
      xb, wqkvb, qkv_b, DIM, nullptr, qb, kb, vtb);

  k_rope<<<2 * BHN * SEQ * 8 / 256, 256, 0, stream>>>(qb, kb, tab);

  k_attn<<<512, 256, 0, stream>>>(qb, kb, vtb, aout);

  k_gemm<0><<<dim3(DIM / 128, MTOK / 128), 256, 0, stream>>>(
      aout, wprojb, proj_b, DIM, out, nullptr, nullptr, nullptr);
}